// Round 3
// baseline (342.920 us; speedup 1.0000x reference)
//
#include <hip/hip_runtime.h>

#define MAXG 4
#define CPB 8                        // channels per block = 4 pairs
#define UCOLS 33                     // region cols 0..32 per row
#define PLANE 991                    // float2 per pair-plane: 30*33=990 used +1 pad (odd)
#define S2LEN (4 * PLANE)            // 3964 float2 = 31712 B
#define NXCD 8
#define CHUNK 64                     // rois per XCD chunk (512 = 8*64)

// Round-3 structure:
//  1) roi_sort_kernel: Morton-sort 512 rois by spatial center -> perm[] in d_ws.
//  2) roi_align_kernel: round-1 body (known-best 57us), but 1D grid decoded as
//     xcd = wgid & 7 so each XCD sweeps 64 spatially-clustered rois per 8-channel
//     group: 64-roi-union x 8ch ~= 0.9 MB fits the 4 MiB XCD L2. The ~3x spatial
//     re-read traffic (ROI boxes overlap 4.1x) moves from L3/HBM service into L2.
// Rationale: R0 occupancy bump null, R2 intra-block pipeline regressed ->
// kernel is memory-SERVICE bound (~440 MB requested / 57 us ~= 7.7 TB/s), not
// latency bound. Only traffic locality can move it.

__global__ void roi_sort_kernel(const float* __restrict__ rois,
                                int* __restrict__ perm, int N) {
    __shared__ unsigned int sk[512];
    const int t = threadIdx.x;
    for (int i = t; i < 512; i += 256) {
        unsigned int key = 0xFFFFFFFFu;          // pad sorts to end
        if (i < N) {
            const float* r = rois + (size_t)i * 5;
            float yc = r[2] + r[4];              // 2*ycenter, [0,~400)
            float xc = r[1] + r[3];              // 2*xcenter, [0,~544)
            unsigned int yq = (unsigned int)min(max((int)(yc * 0.625f),  0), 255);
            unsigned int xq = (unsigned int)min(max((int)(xc * 0.4697f), 0), 255);
            unsigned int x = xq, y = yq;
            x = (x | (x << 4)) & 0x0F0Fu; x = (x | (x << 2)) & 0x3333u; x = (x | (x << 1)) & 0x5555u;
            y = (y | (y << 4)) & 0x0F0Fu; y = (y | (y << 2)) & 0x3333u; y = (y | (y << 1)) & 0x5555u;
            unsigned int mort = (y << 1) | x;    // 16-bit Morton code
            key = (mort << 9) | (unsigned int)i; // payload = roi index (9 bits)
        }
        sk[i] = key;
    }
    __syncthreads();
    for (int k = 2; k <= 512; k <<= 1) {
        for (int j = k >> 1; j > 0; j >>= 1) {
            for (int i = t; i < 512; i += 256) {
                const int ixj = i ^ j;
                if (ixj > i) {
                    unsigned int a = sk[i], b = sk[ixj];
                    const bool up = ((i & k) == 0);
                    if (up ? (a > b) : (a < b)) { sk[i] = b; sk[ixj] = a; }
                }
            }
            __syncthreads();
        }
    }
    for (int i = t; i < 512; i += 256)
        if (i < N) perm[i] = (int)(sk[i] & 511u);
}

__global__ __launch_bounds__(256, 5) void roi_align_kernel(
    const float* __restrict__ feat,
    const float* __restrict__ rois,
    const int* __restrict__ perm,
    float* __restrict__ out,
    int C, int H, int W, int N)
{
    // --- XCD-chunk decode: wgid%8 = XCD (dispatch round-robin heuristic)
    const int wg   = blockIdx.x;
    const int xcd  = wg & (NXCD - 1);
    const int sfl  = wg >> 3;
    const int slot = sfl & (CHUNK - 1);
    const int cblk = sfl >> 6;                   // / CHUNK
    const int nidx = (xcd << 6) + slot;
    if (nidx >= N) return;
    const int n = perm[nidx];
    const int t = threadIdx.x;

    __shared__ float2 s_feat2[S2LEN];
    __shared__ int4   s_ypack[28];   // {(lo-y0)*33, (hi-y0)*33, bits(wy0), bits(wy1)}
    __shared__ int4   s_xpack[28];   // {(xlo-x0a), (xhi-x0a), bits(wx0), bits(wx1)}

    const float* roi = rois + (size_t)n * 5;
    const int   b  = (int)roi[0];
    const float x1 = roi[1], y1 = roi[2], x2 = roi[3], y2 = roi[4];
    const float roi_w = fmaxf(x2 - x1, 1.0f);
    const float roi_h = fmaxf(y2 - y1, 1.0f);
    const float bin_h = roi_h / 7.0f;
    const float bin_w = roi_w / 7.0f;
    int gh = (int)ceilf(roi_h / 7.0f); gh = min(max(gh, 1), MAXG);
    int gw = (int)ceilf(roi_w / 7.0f); gw = min(max(gw, 1), MAXG);
    const float inv_count = 1.0f / (float)(gh * gw);

    auto lo_of = [](float pos, int size) {
        float p = fmaxf(pos, 0.0f);
        return min((int)floorf(p), size - 1);
    };
    const int y0 = lo_of(y1 + 0.5f * bin_h / (float)gh, H);
    const int yE = min(lo_of(y1 + 6.0f * bin_h + ((float)(gh - 1) + 0.5f) * bin_h / (float)gh, H) + 1, H - 1);
    const int x0 = lo_of(x1 + 0.5f * bin_w / (float)gw, W);
    const int xE = min(lo_of(x1 + 6.0f * bin_w + ((float)(gw - 1) + 0.5f) * bin_w / (float)gw, W) + 1, W - 1);
    const int rh    = min(yE - y0 + 1, 30);
    const int x0a   = x0 & ~3;                   // 16B-align region start
    const int spanA = min(xE - x0a + 1, 33);     // cols needed from x0a (<=33)
    const int CM    = W - 4 - x0a;               // max in-row aligned quad start

    // --- geometry tables (y offsets premultiplied into float2-index units)
    if (t < 28) {
        const int py = t >> 2, g = t & 3;
        float pos  = y1 + (float)py * bin_h + ((float)g + 0.5f) * bin_h / (float)gh;
        bool valid = (pos >= -1.0f) && (pos <= (float)H);
        float p = fmaxf(pos, 0.0f);
        int lo  = min((int)floorf(p), H - 1);
        int hi  = min(lo + 1, H - 1);
        if (lo >= H - 1) p = (float)(H - 1);
        float frac = p - (float)lo;
        float m = valid ? 1.0f : 0.0f;
        s_ypack[t] = make_int4((lo - y0) * UCOLS, (hi - y0) * UCOLS,
                               __float_as_int((1.0f - frac) * m),
                               __float_as_int(frac * m));
    } else if (t < 56) {
        const int u = t - 28;
        const int px = u >> 2, g = u & 3;
        float pos  = x1 + (float)px * bin_w + ((float)g + 0.5f) * bin_w / (float)gw;
        bool valid = (pos >= -1.0f) && (pos <= (float)W);
        float p = fmaxf(pos, 0.0f);
        int lo  = min((int)floorf(p), W - 1);
        int hi  = min(lo + 1, W - 1);
        if (lo >= W - 1) p = (float)(W - 1);
        float frac = p - (float)lo;
        float m = valid ? 1.0f : 0.0f;
        s_xpack[u] = make_int4(lo - x0a, hi - x0a,
                               __float_as_int((1.0f - frac) * m),
                               __float_as_int(frac * m));
    }

    // --- staging: transpose [ch][row][col] -> per-pair planes in LDS
    {
        const int  p    = t & 3;
        const int  q    = (t >> 2) & 7;
        const int  r0   = t >> 5;
        const int  q4   = q << 2;
        const bool qon  = (q4 < spanA);
        const int  colA = min(q4, CM);           // in-row aligned; dup writes benign
        const bool tail = (q == 7) && (spanA == 33);

        const size_t HW = (size_t)H * W;
        const int c0 = cblk * CPB;
        const float* fbase = feat + ((size_t)b * C + c0) * HW + (size_t)y0 * W + x0a;
        const float* ga = fbase + (size_t)(2 * p) * HW;
        float2* sb = s_feat2 + p * PLANE;

        #pragma unroll
        for (int k = 0; k < 4; ++k) {
            const int r = r0 + (k << 3);
            if (r < rh) {
                const float* gp = ga + (size_t)r * W;
                if (qon) {
                    const float4 va = *(const float4*)(gp + colA);
                    const float4 vb = *(const float4*)(gp + HW + colA);
                    float2* sp = sb + r * UCOLS + colA;
                    sp[0] = make_float2(va.x, vb.x);
                    sp[1] = make_float2(va.y, vb.y);
                    sp[2] = make_float2(va.z, vb.z);
                    sp[3] = make_float2(va.w, vb.w);
                }
                if (tail) {                      // col 32 (x0a+32 <= W-1 here)
                    sb[r * UCOLS + 32] = make_float2(gp[32], gp[HW + 32]);
                }
            }
        }
    }
    __syncthreads();

    // --- compute: thread = (pixel t>>2, channel-pair t&3); taps are b64 reads
    if (t < 196) {
        const int p   = t & 3;
        const int pix = t >> 2;
        const int py  = pix / 7;
        const int px  = pix - py * 7;
        const float2* sp = s_feat2 + p * PLANE;

        int4 xp[4];
        #pragma unroll
        for (int g = 0; g < 4; ++g) xp[g] = s_xpack[(px << 2) + g];

        float ax = 0.0f, ay = 0.0f;
        #pragma unroll
        for (int gy = 0; gy < MAXG; ++gy) {
            if (gy < gh) {
                const int4 yp = s_ypack[(py << 2) + gy];
                const float wy0 = __int_as_float(yp.z);
                const float wy1 = __int_as_float(yp.w);
                #pragma unroll
                for (int gx = 0; gx < MAXG; ++gx) {
                    if (gx < gw) {
                        const float wx0 = __int_as_float(xp[gx].z);
                        const float wx1 = __int_as_float(xp[gx].w);
                        const float2 v00 = sp[yp.x + xp[gx].x];
                        const float2 v01 = sp[yp.x + xp[gx].y];
                        const float2 v10 = sp[yp.y + xp[gx].x];
                        const float2 v11 = sp[yp.y + xp[gx].y];
                        ax += wy0 * (wx0 * v00.x + wx1 * v01.x)
                            + wy1 * (wx0 * v10.x + wx1 * v11.x);
                        ay += wy0 * (wx0 * v00.y + wx1 * v01.y)
                            + wy1 * (wx0 * v10.y + wx1 * v11.y);
                    }
                }
            }
        }
        const size_t ob = ((size_t)n * C + cblk * CPB + 2 * p) * 49 + pix;
        out[ob]      = ax * inv_count;   // channel 2p
        out[ob + 49] = ay * inv_count;   // channel 2p+1
    }
}

extern "C" void kernel_launch(void* const* d_in, const int* in_sizes, int n_in,
                              void* d_out, int out_size, void* d_ws, size_t ws_size,
                              hipStream_t stream) {
    const float* feat = (const float*)d_in[0];
    const float* rois = (const float*)d_in[1];
    float* out = (float*)d_out;
    int* perm = (int*)d_ws;

    const int C = 256, H = 200, W = 272;
    const int N = in_sizes[1] / 5;   // 512

    roi_sort_kernel<<<1, 256, 0, stream>>>(rois, perm, N);

    dim3 grid(NXCD * CHUNK * (C / CPB));   // 8*64*32 = 16384 blocks, 1D
    roi_align_kernel<<<grid, 256, 0, stream>>>(feat, rois, perm, out, C, H, W, N);
}